// Round 8
// baseline (408.658 us; speedup 1.0000x reference)
//
#include <hip/hip_runtime.h>
#include <math.h>

#define TLEN 1024
#define BSZ  16
#define DIN  128
#define KP   16
#define NEIG 64
#define MOUT 128
#define CHUNK_T 256
#define NCHUNK  4

// ws layout (float units)
static constexpr size_t XCQ_OFF = 0;        // 262144: xc f32 [t][b][k]
static constexpr size_t LAM_OFF = 262144;   // 2048:  lambda c32
static constexpr size_t BQ_OFF  = 264192;   // 2048:  B' c32
static constexpr size_t CP_OFF  = 266240;   // 262144: Cp c32 [(k*64+j)*128+m]
static constexpr size_t ST_OFF  = 528384;   // 65536: scan state
static constexpr size_t S2_OFF  = 593920;   // 8388608: s2 chunk [4096][1024] float2
static constexpr size_t P_OFF   = 8982528;  // 1048576: k-split partials [2][4096][128]
// total: 10,031,104 floats = 40.1 MB (ws >= 69.7 MB proven in rounds 1-2)

__device__ __forceinline__ float f32cos(float x) { return (float)cos((double)x); }
__device__ __forceinline__ float f32sin(float x) { return (float)sin((double)x); }

__device__ __forceinline__ float2 cdiv32(float ar, float ai, float cr, float ci) {
  float2 o;
  if (fabsf(ci) <= fabsf(cr)) {
    float rat = __fdiv_rn(ci, cr);
    float scl = __fdiv_rn(1.0f, __fadd_rn(cr, __fmul_rn(ci, rat)));
    o.x = __fmul_rn(__fadd_rn(ar, __fmul_rn(ai, rat)), scl);
    o.y = __fmul_rn(__fsub_rn(ai, __fmul_rn(ar, rat)), scl);
  } else {
    float rat = __fdiv_rn(cr, ci);
    float scl = __fdiv_rn(1.0f, __fadd_rn(ci, __fmul_rn(cr, rat)));
    o.x = __fmul_rn(__fadd_rn(__fmul_rn(ar, rat), ai), scl);
    o.y = __fmul_rn(__fsub_rn(__fmul_rn(ai, rat), ar), scl);
  }
  return o;
}

// ---------------------------------------------------------------------------
__global__ __launch_bounds__(256) void k_lam_B(const float* __restrict__ theta,
                        float2* __restrict__ lam, float2* __restrict__ Bq) {
  __shared__ float2 terms[4][64];
  int wid  = threadIdx.x >> 6;
  int lane = threadIdx.x & 63;
  int idx = blockIdx.x * 4 + wid;
  int k = idx >> 6, j = idx & 63;
  float thj = (j < 32) ? theta[k * 32 + j] : -theta[k * 32 + (j - 32)];
  float ljr = f32cos(thj), lji = f32sin(thj);
  float2 tm = make_float2(0.f, 0.f);
  if (lane != j) {
    int i = lane;
    float thi = (i < 32) ? theta[k * 32 + i] : -theta[k * 32 + (i - 32)];
    float lir = f32cos(thi), lii = f32sin(thi);
    float2 r = cdiv32(lir, lii, ljr, lji);
    float tr = __fsub_rn(1.0f, r.x);
    float ti = __fsub_rn(0.0f, r.y);
    double h = sqrt((double)tr * tr + (double)ti * ti);
    tm.x = (float)log(h);
    tm.y = (float)atan2((double)ti, (double)tr);
  }
  terms[wid][lane] = tm;
  __syncthreads();
  if (lane == 0) {
    lam[idx] = make_float2(ljr, lji);
    float sr = 0.f, si = 0.f;
    for (int i = 0; i < NEIG; ++i) {
      sr = __fadd_rn(sr, terms[wid][i].x);
      si = __fadd_rn(si, terms[wid][i].y);
    }
    float er = (float)exp((double)(-sr));
    float cc = f32cos(-si), ss = f32sin(-si);
    Bq[idx] = make_float2(__fmul_rn(er, cc), __fmul_rn(er, ss));
  }
}

// ---------------------------------------------------------------------------
__global__ __launch_bounds__(128) void k_Cp(const float* __restrict__ theta,
                     const float* __restrict__ C, float2* __restrict__ Cp) {
  __shared__ float2 sU[64];
  __shared__ float  sC[128][65];
  int tid = threadIdx.x;
  int kj = blockIdx.x;
  int j = kj & 63, k = kj >> 6;
  float lnim = (j < 32) ? theta[k * 32 + j] : -theta[k * 32 + (j - 32)];
  if (tid < 64) {
    int i = tid;
    float p = (float)(63 - i);
    float ph = -__fmul_rn(p, lnim);
    sU[i] = make_float2(f32cos(ph), f32sin(ph));
  }
  const float* Ck = C + ((size_t)k << 13);
  for (int e = tid; e < 128 * 64; e += 128) {
    sC[e >> 6][e & 63] = Ck[e];
  }
  __syncthreads();
  int m = tid;
  float ar = 0.f, ai = 0.f;
  #pragma unroll 8
  for (int i = 0; i < NEIG; ++i) {
    float Cv = sC[m][i];
    float2 U = sU[i];
    ar = __fadd_rn(ar, __fmul_rn(Cv, U.x));
    ai = __fadd_rn(ai, __fmul_rn(Cv, U.y));
  }
  Cp[(size_t)(k * 64 + j) * MOUT + m] = make_float2(ar, ai);
}

// ---------------------------------------------------------------------------
__global__ void k_xc(const float* __restrict__ x, const float* __restrict__ R,
                     float* __restrict__ xcq) {
  int idx = blockIdx.x * blockDim.x + threadIdx.x;
  if (idx >= TLEN * BSZ * KP) return;
  int k = idx & 15;
  int b = (idx >> 4) & 15;
  int t = idx >> 8;
  const float4* xr = (const float4*)(x + ((size_t)b * TLEN + t) * DIN);
  double acc = 0.0;
  #pragma unroll 8
  for (int d4 = 0; d4 < DIN / 4; ++d4) {
    float4 v = xr[d4];
    acc = fma((double)v.x, (double)R[(d4 * 4 + 0) * KP + k], acc);
    acc = fma((double)v.y, (double)R[(d4 * 4 + 1) * KP + k], acc);
    acc = fma((double)v.z, (double)R[(d4 * 4 + 2) * KP + k], acc);
    acc = fma((double)v.w, (double)R[(d4 * 4 + 3) * KP + k], acc);
  }
  xcq[idx] = (float)acc;
}

// ---------------------------------------------------------------------------
// Scan v3: arithmetic bit-identical to round 6; xq window staged in LDS once
// (removes the per-step dependent global load from the recurrence).
__global__ __launch_bounds__(64) void k_scan(const float2* __restrict__ lam,
                        const float2* __restrict__ Bq,
                        const float* __restrict__ xcq,
                        float2* __restrict__ S2,
                        float* __restrict__ state, int c) {
  __shared__ float sXq[CHUNK_T];
  int j = threadIdx.x;                 // 0..63
  int chain = blockIdx.x;              // b*16 + k
  int b = chain >> 4, k = chain & 15;
  int mode = k * 64 + j;
  int t0 = c * CHUNK_T;
  int tlBeg = (c == 0) ? 1 : 0;
  // stage xq window: value used at step tl is xcq[t0+tl-1] = sXq[tl - tlBeg]
  for (int i = j; i < CHUNK_T; i += 64) {
    int g = t0 + tlBeg - 1 + i;        // always in [0, 1023]
    sXq[i] = xcq[(size_t)g * (BSZ * KP) + b * KP + k];
  }
  __syncthreads();
  float lr = lam[mode].x, li = lam[mode].y;
  float Br = Bq[mode].x,  Bi = Bq[mode].y;
  float* st = state + (size_t)(chain * 64 + j) * 4;
  float s1r, s1i, s2r, s2i;
  if (c == 0) { s1r = s1i = s2r = s2i = 0.f; }
  else        { s1r = st[0]; s1i = st[1]; s2r = st[2]; s2i = st[3]; }
  // pipeline prologue: ls = lam*s1 ; al = alpha(ls)
  float lsr = __fsub_rn(__fmul_rn(lr, s1r), __fmul_rn(li, s1i));
  float lsi = __fadd_rn(__fmul_rn(lr, s1i), __fmul_rn(li, s1r));
  float h  = (float)sqrt((double)lsr * lsr + (double)lsi * lsi);
  float al = __fdiv_rn(1.0f, __fsqrt_rn(__fadd_rn(1.0f, __fmul_rn(h, h))));
  if (c == 0)
    S2[(size_t)(0 * BSZ + b) * 1024 + mode] = make_float2(s2r, s2i);
  #pragma unroll 4
  for (int tl = tlBeg; tl < CHUNK_T; ++tl) {
    float xq = sXq[tl - tlBeg];
    float bxr = __fmul_rn(xq, Br), bxi = __fmul_rn(xq, Bi);
    float a2r = __fmul_rn(al, lr), a2i = __fmul_rn(al, li);
    float t2r = __fsub_rn(__fmul_rn(a2r, s2r), __fmul_rn(a2i, s2i));
    float t2i = __fadd_rn(__fmul_rn(a2r, s2i), __fmul_rn(a2i, s2r));
    s2r = __fadd_rn(t2r, bxr);
    s2i = __fadd_rn(t2i, bxi);
    s1r = __fadd_rn(lsr, bxr);
    s1i = __fadd_rn(lsi, bxi);
    lsr = __fsub_rn(__fmul_rn(lr, s1r), __fmul_rn(li, s1i));
    lsi = __fadd_rn(__fmul_rn(lr, s1i), __fmul_rn(li, s1r));
    h  = (float)sqrt((double)lsr * lsr + (double)lsi * lsi);
    al = __fdiv_rn(1.0f, __fsqrt_rn(__fadd_rn(1.0f, __fmul_rn(h, h))));
    S2[(size_t)(tl * BSZ + b) * 1024 + mode] = make_float2(s2r, s2i);
  }
  st[0] = s1r; st[1] = s1i; st[2] = s2r; st[3] = s2i;
}

// ---------------------------------------------------------------------------
// k_y v5: split-k x2 -> 512 blocks (2/CU). BM=32 x BN=64, 256 threads,
// 2 rows (rg, rg+16) x 4 cols per thread. Partial msum over k in [kh*8, kh*8+8)
// written WITHOUT /16 to P[kh]. n-sum and within-half k-sum keep the exact
// sequential f32 order of rounds 4-6.
__global__ __launch_bounds__(256) void k_y(const float2* __restrict__ S2,
                     const float2* __restrict__ Cp, const float* __restrict__ xcq,
                     const float* __restrict__ D, const float* __restrict__ Dov,
                     float* __restrict__ P, int c) {
  __shared__ __align__(16) float2 sS2[32][66];   // [row][mode], 16.9 KB
  __shared__ __align__(16) float2 sCp[64][66];   // [mode][col], 33.8 KB
  int tid = threadIdx.x;
  int bid = blockIdx.x;
  int kh   = bid >> 8;                 // 0/1: k half
  int tile = bid & 255;
  int rowBase = (tile >> 1) * 32;      // chunk-local row
  int colBase = (tile & 1) * 64;
  int rg = tid & 15;                   // rows rg, rg+16
  int cg = tid >> 4;                   // cols cg*4 .. +3
  int c0 = cg * 4;
  float msum[2][4] = {};
  int kbeg = kh * 8;
  for (int kk = 0; kk < 8; ++kk) {
    int k = kbeg + kk;
    __syncthreads();
    // stage S2 tile [32][64] float2: 1024 float4s, 4/thread
    #pragma unroll
    for (int it = 0; it < 4; ++it) {
      int e = tid + it * 256;
      int r = e >> 5, q = e & 31;
      float4 v = *(const float4*)(S2 + (size_t)(rowBase + r) * 1024 + k * 64 + q * 2);
      *(float4*)&sS2[r][q * 2] = v;
    }
    // stage Cp tile [64][64] float2: 2048 float4s, 8/thread
    #pragma unroll
    for (int it = 0; it < 8; ++it) {
      int e = tid + it * 256;
      int n = e >> 5, q = e & 31;
      float4 v = *(const float4*)(Cp + (size_t)(k * 64 + n) * MOUT + colBase + q * 2);
      *(float4*)&sCp[n][q * 2] = v;
    }
    __syncthreads();
    float accn[2][4] = {};
    #pragma unroll 4
    for (int n = 0; n < 64; ++n) {
      float2 sA = sS2[rg][n];
      float2 sB = sS2[rg + 16][n];
      float4 cpA = *(const float4*)&sCp[n][c0];      // cols c0, c0+1
      float4 cpB = *(const float4*)&sCp[n][c0 + 2];  // cols c0+2, c0+3
      float cx[4] = {cpA.x, cpA.z, cpB.x, cpB.z};
      float cy[4] = {cpA.y, cpA.w, cpB.y, cpB.w};
      #pragma unroll
      for (int cc = 0; cc < 4; ++cc) {
        accn[0][cc] = __fadd_rn(accn[0][cc],
            __fsub_rn(__fmul_rn(sA.x, cx[cc]), __fmul_rn(sA.y, cy[cc])));
        accn[1][cc] = __fadd_rn(accn[1][cc],
            __fsub_rn(__fmul_rn(sB.x, cx[cc]), __fmul_rn(sB.y, cy[cc])));
      }
    }
    // epilogue per k (order matches rounds 4-6)
    float4 dA = *(const float4*)(D + k * MOUT + colBase + c0);
    float4 oA = *(const float4*)(Dov + colBase + c0);
    float dv[4] = {dA.x, dA.y, dA.z, dA.w};
    float ov[4] = {oA.x, oA.y, oA.z, oA.w};
    float xv0 = xcq[(size_t)(c * 4096 + rowBase + rg) * KP + k];
    float xv1 = xcq[(size_t)(c * 4096 + rowBase + rg + 16) * KP + k];
    #pragma unroll
    for (int cc = 0; cc < 4; ++cc) {
      float y0 = __fadd_rn(accn[0][cc], __fmul_rn(xv0, dv[cc]));
      float y1 = __fadd_rn(accn[1][cc], __fmul_rn(xv1, dv[cc]));
      y0 = __fadd_rn(y0, ov[cc]);
      y1 = __fadd_rn(y1, ov[cc]);
      msum[0][cc] = __fadd_rn(msum[0][cc], y0);
      msum[1][cc] = __fadd_rn(msum[1][cc], y1);
    }
  }
  #pragma unroll
  for (int rr = 0; rr < 2; ++rr) {
    int r = rowBase + rg + rr * 16;
    float* pp = P + ((size_t)kh * 4096 + r) * MOUT + colBase + c0;
    *(float4*)pp = make_float4(msum[rr][0], msum[rr][1], msum[rr][2], msum[rr][3]);
  }
}

// ---------------------------------------------------------------------------
// out = (P0 + P1) / 16, scattered to [b][t][m] layout.
__global__ __launch_bounds__(256) void k_combine(const float* __restrict__ P,
                     float* __restrict__ out, int c) {
  int idx = blockIdx.x * 256 + threadIdx.x;   // 131072 float4s
  int r  = idx >> 5;
  int m4 = (idx & 31) * 4;
  float4 p0 = *(const float4*)(P + (size_t)r * MOUT + m4);
  float4 p1 = *(const float4*)(P + ((size_t)4096 + r) * MOUT + m4);
  int rg = c * 4096 + r;
  int t = rg >> 4, b = rg & 15;
  float4 res;
  res.x = __fdiv_rn(__fadd_rn(p0.x, p1.x), 16.0f);
  res.y = __fdiv_rn(__fadd_rn(p0.y, p1.y), 16.0f);
  res.z = __fdiv_rn(__fadd_rn(p0.z, p1.z), 16.0f);
  res.w = __fdiv_rn(__fadd_rn(p0.w, p1.w), 16.0f);
  *(float4*)(out + ((size_t)b * TLEN + t) * MOUT + m4) = res;
}

// ---------------------------------------------------------------------------
extern "C" void kernel_launch(void* const* d_in, const int* in_sizes, int n_in,
                              void* d_out, int out_size, void* d_ws, size_t ws_size,
                              hipStream_t stream) {
  const float* x     = (const float*)d_in[0];
  const float* R     = (const float*)d_in[1];
  const float* theta = (const float*)d_in[2];
  const float* C     = (const float*)d_in[3];
  const float* D     = (const float*)d_in[4];
  const float* Do    = (const float*)d_in[5];
  float* out = (float*)d_out;
  float* ws  = (float*)d_ws;
  float*  xcq = ws + XCQ_OFF;
  float2* lam = (float2*)(ws + LAM_OFF);
  float2* Bq  = (float2*)(ws + BQ_OFF);
  float2* Cp  = (float2*)(ws + CP_OFF);
  float*  st  = ws + ST_OFF;
  float2* S2  = (float2*)(ws + S2_OFF);
  float*  P   = ws + P_OFF;

  hipLaunchKernelGGL(k_lam_B, dim3(256),  dim3(256), 0, stream, theta, lam, Bq);
  hipLaunchKernelGGL(k_Cp,    dim3(1024), dim3(128), 0, stream, theta, C, Cp);
  hipLaunchKernelGGL(k_xc,    dim3(1024), dim3(256), 0, stream, x, R, xcq);
  for (int c = 0; c < NCHUNK; ++c) {
    hipLaunchKernelGGL(k_scan,    dim3(256), dim3(64),  0, stream, lam, Bq, xcq, S2, st, c);
    hipLaunchKernelGGL(k_y,       dim3(512), dim3(256), 0, stream, S2, Cp, xcq, D, Do, P, c);
    hipLaunchKernelGGL(k_combine, dim3(512), dim3(256), 0, stream, P, out, c);
  }
}

// Round 9
// 379.793 us; speedup vs baseline: 1.0760x; 1.0760x over previous
//
#include <hip/hip_runtime.h>
#include <math.h>

#define TLEN 1024
#define BSZ  16
#define DIN  128
#define KP   16
#define NEIG 64
#define MOUT 128
#define CHUNK_T 256
#define NCHUNK  4

// ws layout (float units)
static constexpr size_t XCQ_OFF = 0;        // 262144: xc f32 [t][b][k]
static constexpr size_t LAM_OFF = 262144;   // 2048:  lambda c32
static constexpr size_t BQ_OFF  = 264192;   // 2048:  B' c32
static constexpr size_t CP_OFF  = 266240;   // 262144: Cp c32 [(k*64+j)*128+m]
static constexpr size_t ST_OFF  = 528384;   // 65536: scan state
static constexpr size_t S2_OFF  = 593920;   // 8388608: s2 chunk [4096][1024] float2
static constexpr size_t P_OFF   = 8982528;  // 8388608: k-split partials [16][4096][128]
// total: 17,371,136 floats = 69.48 MB (69.75 MB proven usable in rounds 1-2)

__device__ __forceinline__ float f32cos(float x) { return (float)cos((double)x); }
__device__ __forceinline__ float f32sin(float x) { return (float)sin((double)x); }

__device__ __forceinline__ float2 cdiv32(float ar, float ai, float cr, float ci) {
  float2 o;
  if (fabsf(ci) <= fabsf(cr)) {
    float rat = __fdiv_rn(ci, cr);
    float scl = __fdiv_rn(1.0f, __fadd_rn(cr, __fmul_rn(ci, rat)));
    o.x = __fmul_rn(__fadd_rn(ar, __fmul_rn(ai, rat)), scl);
    o.y = __fmul_rn(__fsub_rn(ai, __fmul_rn(ar, rat)), scl);
  } else {
    float rat = __fdiv_rn(cr, ci);
    float scl = __fdiv_rn(1.0f, __fadd_rn(ci, __fmul_rn(cr, rat)));
    o.x = __fmul_rn(__fadd_rn(__fmul_rn(ar, rat), ai), scl);
    o.y = __fmul_rn(__fsub_rn(__fmul_rn(ai, rat), ar), scl);
  }
  return o;
}

// ---------------------------------------------------------------------------
__global__ __launch_bounds__(256) void k_lam_B(const float* __restrict__ theta,
                        float2* __restrict__ lam, float2* __restrict__ Bq) {
  __shared__ float2 terms[4][64];
  int wid  = threadIdx.x >> 6;
  int lane = threadIdx.x & 63;
  int idx = blockIdx.x * 4 + wid;
  int k = idx >> 6, j = idx & 63;
  float thj = (j < 32) ? theta[k * 32 + j] : -theta[k * 32 + (j - 32)];
  float ljr = f32cos(thj), lji = f32sin(thj);
  float2 tm = make_float2(0.f, 0.f);
  if (lane != j) {
    int i = lane;
    float thi = (i < 32) ? theta[k * 32 + i] : -theta[k * 32 + (i - 32)];
    float lir = f32cos(thi), lii = f32sin(thi);
    float2 r = cdiv32(lir, lii, ljr, lji);
    float tr = __fsub_rn(1.0f, r.x);
    float ti = __fsub_rn(0.0f, r.y);
    double h = sqrt((double)tr * tr + (double)ti * ti);
    tm.x = (float)log(h);
    tm.y = (float)atan2((double)ti, (double)tr);
  }
  terms[wid][lane] = tm;
  __syncthreads();
  if (lane == 0) {
    lam[idx] = make_float2(ljr, lji);
    float sr = 0.f, si = 0.f;
    for (int i = 0; i < NEIG; ++i) {
      sr = __fadd_rn(sr, terms[wid][i].x);
      si = __fadd_rn(si, terms[wid][i].y);
    }
    float er = (float)exp((double)(-sr));
    float cc = f32cos(-si), ss = f32sin(-si);
    Bq[idx] = make_float2(__fmul_rn(er, cc), __fmul_rn(er, ss));
  }
}

// ---------------------------------------------------------------------------
__global__ __launch_bounds__(128) void k_Cp(const float* __restrict__ theta,
                     const float* __restrict__ C, float2* __restrict__ Cp) {
  __shared__ float2 sU[64];
  __shared__ float  sC[128][65];
  int tid = threadIdx.x;
  int kj = blockIdx.x;
  int j = kj & 63, k = kj >> 6;
  float lnim = (j < 32) ? theta[k * 32 + j] : -theta[k * 32 + (j - 32)];
  if (tid < 64) {
    int i = tid;
    float p = (float)(63 - i);
    float ph = -__fmul_rn(p, lnim);
    sU[i] = make_float2(f32cos(ph), f32sin(ph));
  }
  const float* Ck = C + ((size_t)k << 13);
  for (int e = tid; e < 128 * 64; e += 128) {
    sC[e >> 6][e & 63] = Ck[e];
  }
  __syncthreads();
  int m = tid;
  float ar = 0.f, ai = 0.f;
  #pragma unroll 8
  for (int i = 0; i < NEIG; ++i) {
    float Cv = sC[m][i];
    float2 U = sU[i];
    ar = __fadd_rn(ar, __fmul_rn(Cv, U.x));
    ai = __fadd_rn(ai, __fmul_rn(Cv, U.y));
  }
  Cp[(size_t)(k * 64 + j) * MOUT + m] = make_float2(ar, ai);
}

// ---------------------------------------------------------------------------
// v3: LDS-stage 16 x-rows + R; one thread per (row,k). f64 fma chain over d
// ascending — bit-identical to prior rounds.
__global__ __launch_bounds__(256) void k_xc(const float* __restrict__ x,
                     const float* __restrict__ R, float* __restrict__ xcq) {
  __shared__ float sX[16][132];
  __shared__ float sR[128][16];
  int tid = threadIdx.x;
  int rBase = blockIdx.x * 16;         // row r = t*16 + b
  for (int e = tid; e < DIN * KP; e += 256) sR[e >> 4][e & 15] = R[e];
  #pragma unroll
  for (int it = 0; it < 2; ++it) {
    int e = tid + it * 256;            // 512 float4s = 16 rows x 32
    int row = e >> 5, q = e & 31;
    int g = rBase + row;
    int t = g >> 4, b = g & 15;
    float4 v = *(const float4*)(x + ((size_t)b * TLEN + t) * DIN + q * 4);
    *(float4*)&sX[row][q * 4] = v;
  }
  __syncthreads();
  int r = tid >> 4, k = tid & 15;
  double acc = 0.0;
  #pragma unroll 16
  for (int d = 0; d < DIN; ++d)
    acc = fma((double)sX[r][d], (double)sR[d][k], acc);
  xcq[(size_t)(rBase + r) * KP + k] = (float)acc;
}

// ---------------------------------------------------------------------------
// Scan v3 (unchanged from round 8): arithmetic bit-identical; xq staged in LDS.
__global__ __launch_bounds__(64) void k_scan(const float2* __restrict__ lam,
                        const float2* __restrict__ Bq,
                        const float* __restrict__ xcq,
                        float2* __restrict__ S2,
                        float* __restrict__ state, int c) {
  __shared__ float sXq[CHUNK_T];
  int j = threadIdx.x;
  int chain = blockIdx.x;              // b*16 + k
  int b = chain >> 4, k = chain & 15;
  int mode = k * 64 + j;
  int t0 = c * CHUNK_T;
  int tlBeg = (c == 0) ? 1 : 0;
  for (int i = j; i < CHUNK_T; i += 64) {
    int g = t0 + tlBeg - 1 + i;
    sXq[i] = xcq[(size_t)g * (BSZ * KP) + b * KP + k];
  }
  __syncthreads();
  float lr = lam[mode].x, li = lam[mode].y;
  float Br = Bq[mode].x,  Bi = Bq[mode].y;
  float* st = state + (size_t)(chain * 64 + j) * 4;
  float s1r, s1i, s2r, s2i;
  if (c == 0) { s1r = s1i = s2r = s2i = 0.f; }
  else        { s1r = st[0]; s1i = st[1]; s2r = st[2]; s2i = st[3]; }
  float lsr = __fsub_rn(__fmul_rn(lr, s1r), __fmul_rn(li, s1i));
  float lsi = __fadd_rn(__fmul_rn(lr, s1i), __fmul_rn(li, s1r));
  float h  = (float)sqrt((double)lsr * lsr + (double)lsi * lsi);
  float al = __fdiv_rn(1.0f, __fsqrt_rn(__fadd_rn(1.0f, __fmul_rn(h, h))));
  if (c == 0)
    S2[(size_t)(0 * BSZ + b) * 1024 + mode] = make_float2(s2r, s2i);
  #pragma unroll 4
  for (int tl = tlBeg; tl < CHUNK_T; ++tl) {
    float xq = sXq[tl - tlBeg];
    float bxr = __fmul_rn(xq, Br), bxi = __fmul_rn(xq, Bi);
    float a2r = __fmul_rn(al, lr), a2i = __fmul_rn(al, li);
    float t2r = __fsub_rn(__fmul_rn(a2r, s2r), __fmul_rn(a2i, s2i));
    float t2i = __fadd_rn(__fmul_rn(a2r, s2i), __fmul_rn(a2i, s2r));
    s2r = __fadd_rn(t2r, bxr);
    s2i = __fadd_rn(t2i, bxi);
    s1r = __fadd_rn(lsr, bxr);
    s1i = __fadd_rn(lsi, bxi);
    lsr = __fsub_rn(__fmul_rn(lr, s1r), __fmul_rn(li, s1i));
    lsi = __fadd_rn(__fmul_rn(lr, s1i), __fmul_rn(li, s1r));
    h  = (float)sqrt((double)lsr * lsr + (double)lsi * lsi);
    al = __fdiv_rn(1.0f, __fsqrt_rn(__fadd_rn(1.0f, __fmul_rn(h, h))));
    S2[(size_t)(tl * BSZ + b) * 1024 + mode] = make_float2(s2r, s2i);
  }
  st[0] = s1r; st[1] = s1i; st[2] = s2r; st[3] = s2i;
}

// ---------------------------------------------------------------------------
// k_y v6: split-k x16, 8x8 microtile. 512 blocks (2/CU). BM=128 x BN=128.
// Thread (rg=tid&15, cg=tid>>4): rows rg+16j (j=0..7), cols cg*8..+7.
// LDS: sS2t[32][129] (transposed, 2-way-free staging) + sCp[32][128]; two
// n-halves per k. n ascending 0..63; per-element ops identical to rounds 4-8.
// P[k] = accn + xc*D[k] + Do (no /16); combine sums k ascending.
__global__ __launch_bounds__(256, 2) void k_y(const float2* __restrict__ S2,
                     const float2* __restrict__ Cp, const float* __restrict__ xcq,
                     const float* __restrict__ D, const float* __restrict__ Dov,
                     float* __restrict__ P, int c) {
  __shared__ float2 sS2t[32][129];   // 33.0 KB [n][row]
  __shared__ float2 sCp[32][128];    // 32.8 KB [n][col]
  int tid = threadIdx.x;
  int kidx = blockIdx.x >> 5;        // 0..15
  int rt   = blockIdx.x & 31;        // 0..31
  int rowBase = rt * 128;            // chunk-local
  int rg = tid & 15;
  int cg = tid >> 4;
  int c0 = cg * 8;
  float acc[8][8];
  #pragma unroll
  for (int jj = 0; jj < 8; ++jj)
    #pragma unroll
    for (int q = 0; q < 8; ++q) acc[jj][q] = 0.f;

  #pragma unroll 1
  for (int nh = 0; nh < 2; ++nh) {
    __syncthreads();
    // stage sS2t [32 n][128 row]: float4 = 2 consecutive n of one row
    #pragma unroll
    for (int it = 0; it < 8; ++it) {
      int e = tid + it * 256;          // 0..2047
      int n2 = (e & 15) * 2;
      int row = e >> 4;                // 0..127
      float4 v = *(const float4*)(S2 + (size_t)(rowBase + row) * 1024
                                     + kidx * 64 + nh * 32 + n2);
      sS2t[n2][row]     = make_float2(v.x, v.y);
      sS2t[n2 + 1][row] = make_float2(v.z, v.w);
    }
    // stage sCp [32 n][128 col]: float4 = 2 cols, linear
    #pragma unroll
    for (int it = 0; it < 8; ++it) {
      int e = tid + it * 256;
      int col2 = (e & 63) * 2;
      int n = e >> 6;                  // 0..31
      float4 v = *(const float4*)(Cp + (size_t)(kidx * 64 + nh * 32 + n) * MOUT + col2);
      *(float4*)&sCp[n][col2] = v;
    }
    __syncthreads();
    #pragma unroll 2
    for (int n = 0; n < 32; ++n) {
      float2 a[8];
      #pragma unroll
      for (int jj = 0; jj < 8; ++jj) a[jj] = sS2t[n][rg + jj * 16];
      float4 w[4];
      #pragma unroll
      for (int q = 0; q < 4; ++q) w[q] = *(const float4*)&sCp[n][c0 + q * 2];
      float cx[8] = {w[0].x, w[0].z, w[1].x, w[1].z, w[2].x, w[2].z, w[3].x, w[3].z};
      float cy[8] = {w[0].y, w[0].w, w[1].y, w[1].w, w[2].y, w[2].w, w[3].y, w[3].w};
      #pragma unroll
      for (int jj = 0; jj < 8; ++jj)
        #pragma unroll
        for (int q = 0; q < 8; ++q)
          acc[jj][q] = __fadd_rn(acc[jj][q],
              __fsub_rn(__fmul_rn(a[jj].x, cx[q]), __fmul_rn(a[jj].y, cy[q])));
    }
  }
  // epilogue: P[kidx][row][col] = accn + xc*D[kidx] + Do  (op order as before)
  float dv[8], ovv[8];
  *(float4*)&dv[0]  = *(const float4*)(D + kidx * MOUT + c0);
  *(float4*)&dv[4]  = *(const float4*)(D + kidx * MOUT + c0 + 4);
  *(float4*)&ovv[0] = *(const float4*)(Dov + c0);
  *(float4*)&ovv[4] = *(const float4*)(Dov + c0 + 4);
  #pragma unroll
  for (int jj = 0; jj < 8; ++jj) {
    int row = rowBase + rg + jj * 16;
    float xv = xcq[(size_t)(c * 4096 + row) * KP + kidx];
    float res[8];
    #pragma unroll
    for (int q = 0; q < 8; ++q)
      res[q] = __fadd_rn(__fadd_rn(acc[jj][q], __fmul_rn(xv, dv[q])), ovv[q]);
    float* pp = P + ((size_t)kidx * 4096 + row) * MOUT + c0;
    *(float4*)pp       = make_float4(res[0], res[1], res[2], res[3]);
    *(float4*)(pp + 4) = make_float4(res[4], res[5], res[6], res[7]);
  }
}

// ---------------------------------------------------------------------------
// out = (P0 + P1 + ... + P15)/16, k ascending (bit-matches rounds 4-6 msum).
__global__ __launch_bounds__(256) void k_combine(const float* __restrict__ P,
                     float* __restrict__ out, int c) {
  int idx = blockIdx.x * 256 + threadIdx.x;   // 131072 float4s
  int r  = idx >> 5;                           // 0..4095
  int m4 = (idx & 31) * 4;
  float4 s = *(const float4*)(P + (size_t)r * MOUT + m4);
  #pragma unroll
  for (int k = 1; k < KP; ++k) {
    float4 p = *(const float4*)(P + ((size_t)k * 4096 + r) * MOUT + m4);
    s.x = __fadd_rn(s.x, p.x);
    s.y = __fadd_rn(s.y, p.y);
    s.z = __fadd_rn(s.z, p.z);
    s.w = __fadd_rn(s.w, p.w);
  }
  int rg = c * 4096 + r;
  int t = rg >> 4, b = rg & 15;
  float4 res;
  res.x = __fdiv_rn(s.x, 16.0f);
  res.y = __fdiv_rn(s.y, 16.0f);
  res.z = __fdiv_rn(s.z, 16.0f);
  res.w = __fdiv_rn(s.w, 16.0f);
  *(float4*)(out + ((size_t)b * TLEN + t) * MOUT + m4) = res;
}

// ---------------------------------------------------------------------------
extern "C" void kernel_launch(void* const* d_in, const int* in_sizes, int n_in,
                              void* d_out, int out_size, void* d_ws, size_t ws_size,
                              hipStream_t stream) {
  const float* x     = (const float*)d_in[0];
  const float* R     = (const float*)d_in[1];
  const float* theta = (const float*)d_in[2];
  const float* C     = (const float*)d_in[3];
  const float* D     = (const float*)d_in[4];
  const float* Do    = (const float*)d_in[5];
  float* out = (float*)d_out;
  float* ws  = (float*)d_ws;
  float*  xcq = ws + XCQ_OFF;
  float2* lam = (float2*)(ws + LAM_OFF);
  float2* Bq  = (float2*)(ws + BQ_OFF);
  float2* Cp  = (float2*)(ws + CP_OFF);
  float*  st  = ws + ST_OFF;
  float2* S2  = (float2*)(ws + S2_OFF);
  float*  P   = ws + P_OFF;

  hipLaunchKernelGGL(k_lam_B, dim3(256),  dim3(256), 0, stream, theta, lam, Bq);
  hipLaunchKernelGGL(k_Cp,    dim3(1024), dim3(128), 0, stream, theta, C, Cp);
  hipLaunchKernelGGL(k_xc,    dim3(1024), dim3(256), 0, stream, x, R, xcq);
  for (int c = 0; c < NCHUNK; ++c) {
    hipLaunchKernelGGL(k_scan,    dim3(256), dim3(64),  0, stream, lam, Bq, xcq, S2, st, c);
    hipLaunchKernelGGL(k_y,       dim3(512), dim3(256), 0, stream, S2, Cp, xcq, D, Do, P, c);
    hipLaunchKernelGGL(k_combine, dim3(512), dim3(256), 0, stream, P, out, c);
  }
}